// Round 1
// baseline (481.442 us; speedup 1.0000x reference)
//
#include <hip/hip_runtime.h>

// ============================================================================
// GaussianBlur2D: separable 201-tap Gaussian (sigma=25, zero-pad), fp32 I/O.
// T=64, H=544, W=960.
//
// MFMA path (new): both passes are banded-Toeplitz matmuls on the matrix pipe
// (v_mfma_f32_16x16x32_f16, 2.2 PF ceiling) instead of fp32 VALU (157 TF).
//   pass1: vertical conv, fp32 in -> f16 intermediate (transposed, in d_ws)
//          data split x = hi + lo*2^-11 (two f16 MFMA products)
//   pass2: "vertical" conv over w on the transposed intermediate, f16 in ->
//          fp32 out (transposed back = final layout), single MFMA product.
// Taps are f16 scaled x1024 (edge taps stay normal); exact /1024 at store.
// Numerics: adds <= ~5e-4 worst-case to the fp32 path's measured 0.0039.
// Fallback: if ws_size < 67MB, run the previous fp32 vpass/hpass (472us).
// ============================================================================

typedef _Float16 half8 __attribute__((ext_vector_type(8)));
typedef float    f32x4 __attribute__((ext_vector_type(4)));
typedef unsigned short u16;
typedef unsigned int   u32;

#define HH   544
#define WWD  960
#define PADC 100
#define RV   32

// ---- compile-time Gaussian (double Taylor exp, rounded to f32) ----
constexpr double cexp_taylor(double x) {
  double term = 1.0, sum = 1.0;
  for (int n = 1; n < 120; ++n) { term *= x / n; sum += term; }
  return sum;
}
constexpr float gaussk(int k) {            // tap k in [0,200] -> g(k-100), else 0
  if (k < 0 || k > 200) return 0.0f;
  double r = (double)(k - PADC);
  return (float)(cexp_taylor(-(r * r) / (2.0 * 25.0 * 25.0))
                 / (25.0 * 2.5066282746310002));
}

// f32 zero-padded tap table for the MFMA path: G0.v[v] = g(v-140), v in [0,288)
struct G0T { float v[288]; };
constexpr G0T make_g0() {
  G0T t{};
  for (int i = 0; i < 288; ++i) t.v[i] = gaussk(i - 40);
  return t;
}
__device__ __constant__ G0T G0 = make_g0();

// ============================================================================
// Generic transposing banded conv:
//   in : 64 frames of R rows x C cols (row-major), conv along rows (dim R)
//   out: 64 frames of C rows x R cols  -> out[t][c][r] = sum_b g(b) in[t][r+b][c]
// IN16=false: fp32 in, f16 out (pass 1).  IN16=true: f16 in, fp32 out (pass 2).
// Block: 256 threads = 4 waves; 64x64 output tile (4 m-subtiles x 4 wave-cols).
// K-loop: 9 steps of 32 input rows starting at m0-100; (i,t) active iff
// t in [i>>1, (i>>1)+6+(i&1)]  (30 of 36 pairs -> 216/201 band overhead).
// A (Toeplitz taps): LDS table P[264] of packed f16x8, P[e].b = 1024*g(e-132-b);
//   fragment for (i,t) = P[moff + 16i - 32t], moff = (l&15) - 8*(l>>4) + 232.
// B (data): 32x64 tile staged transposed to LDS as f16 (hi[,lo]), 16B-group
//   XOR swizzle gg = g ^ ((n>>1)&3) -> conflict-free b128 on both sides.
// MFMA: D[m][n], m(out row)=4*(l>>4)+reg, n(out col)=l&15  [m91-verified C/D].
// ============================================================================
template<int R, int C, bool IN16>
__global__ __launch_bounds__(256, 4) void gconvT(const void* __restrict__ inv,
                                                 void* __restrict__ outv) {
  constexpr int NB = (C + 63) / 64;
  constexpr int MB = (R + 63) / 64;
  constexpr int BPF = MB * NB;               // 135 blocks per frame (both passes)

  const int lid = blockIdx.x;
  const int xcd = lid & 7;                   // frame -> XCD affinity (L2 locality)
  const int s   = lid >> 3;
  const int f   = s / BPF;
  const int r135 = s - f * BPF;
  const int tf  = (f << 3) | xcd;            // frame 0..63
  const int mb  = r135 / NB;
  const int nb  = r135 - mb * NB;
  const int m0  = mb * 64, n0 = nb * 64;
  const int imax = (R - m0) >> 4 < 4 ? (R - m0) >> 4 : 4;

  const int tid = threadIdx.x;

  __shared__ uint4 Ptab4[264];
  __shared__ uint4 Bhi4[256];
  __shared__ uint4 Blo4[IN16 ? 1 : 256];

  // ---- build packed tap table in LDS (once per block) ----
  {
    int e = tid;
#pragma unroll
    for (int rep = 0; rep < 2; ++rep, e += 256) {
      if (e < 264) {
        u32 w[4];
#pragma unroll
        for (int p = 0; p < 4; ++p) {
          float f0 = G0.v[e + 8 - 2 * p];        // elem b=2p   : g(e-132-b)
          float f1 = G0.v[e + 7 - 2 * p];        // elem b=2p+1
          u16 h0 = __builtin_bit_cast(u16, (_Float16)(f0 * 1024.0f));
          u16 h1 = __builtin_bit_cast(u16, (_Float16)(f1 * 1024.0f));
          w[p] = (u32)h0 | ((u32)h1 << 16);
        }
        uint4 q; q.x = w[0]; q.y = w[1]; q.z = w[2]; q.w = w[3];
        Ptab4[e] = q;
      }
    }
  }

  // staging-side ids
  const int nl = tid & 63;                   // LDS column (data col within tile)
  const int gW = tid >> 6;                   // wave id = kk-group staged
  const int kb0 = m0 - PADC;
  const int cc_raw = n0 + nl;
  const int cc = cc_raw < C - 1 ? cc_raw : C - 1;   // clamp col (pass2 tail)
  const size_t fofs = (size_t)tf * R * C;

  // compute-side ids
  const int l   = tid & 63;
  const int wi  = tid >> 6;
  const int n16 = l & 15, g4 = l >> 4;
  const int nl2 = 16 * wi + n16;
  const int moff = n16 - 8 * g4 + 232;
  const int ggB  = g4 ^ ((n16 >> 1) & 3);

  f32x4 accH[4], accL[4];
#pragma unroll
  for (int i = 0; i < 4; ++i) {
    accH[i] = (f32x4){0.f, 0.f, 0.f, 0.f};
    accL[i] = (f32x4){0.f, 0.f, 0.f, 0.f};
  }

#pragma unroll
  for (int t = 0; t < 9; ++t) {
    __syncthreads();                         // protects P on t=0, B reads after
    // ---- stage 32 rows x 64 cols, transposed+split, into LDS ----
    {
      const int rb = kb0 + 32 * t + 8 * gW;
      const int gg = gW ^ ((nl >> 1) & 3);
      if constexpr (!IN16) {
        const float* inf = (const float*)inv + fofs;
        float v[8];
#pragma unroll
        for (int jj = 0; jj < 8; ++jj) {
          const int rr = rb + jj;
          const int rc = rr < 0 ? 0 : (rr > R - 1 ? R - 1 : rr);
          float xv = inf[(size_t)rc * C + cc];
          v[jj] = (rr == rc) ? xv : 0.0f;    // zero-pad rows
        }
        u16 hu[8], lu[8];
#pragma unroll
        for (int jj = 0; jj < 8; ++jj) {
          const _Float16 h = (_Float16)v[jj];
          const float hf = (float)h;
          const _Float16 lo = (_Float16)((v[jj] - hf) * 2048.0f);
          hu[jj] = __builtin_bit_cast(u16, h);
          lu[jj] = __builtin_bit_cast(u16, lo);
        }
        uint4 qh, ql;
        qh.x = (u32)hu[0] | ((u32)hu[1] << 16);
        qh.y = (u32)hu[2] | ((u32)hu[3] << 16);
        qh.z = (u32)hu[4] | ((u32)hu[5] << 16);
        qh.w = (u32)hu[6] | ((u32)hu[7] << 16);
        ql.x = (u32)lu[0] | ((u32)lu[1] << 16);
        ql.y = (u32)lu[2] | ((u32)lu[3] << 16);
        ql.z = (u32)lu[4] | ((u32)lu[5] << 16);
        ql.w = (u32)lu[6] | ((u32)lu[7] << 16);
        Bhi4[nl * 4 + gg] = qh;
        Blo4[nl * 4 + gg] = ql;
      } else {
        const u16* inf = (const u16*)inv + fofs;
        u16 hu[8];
#pragma unroll
        for (int jj = 0; jj < 8; ++jj) {
          const int rr = rb + jj;
          const int rc = rr < 0 ? 0 : (rr > R - 1 ? R - 1 : rr);
          u16 xv = inf[(size_t)rc * C + cc];
          hu[jj] = (rr == rc) ? xv : (u16)0;
        }
        uint4 qh;
        qh.x = (u32)hu[0] | ((u32)hu[1] << 16);
        qh.y = (u32)hu[2] | ((u32)hu[3] << 16);
        qh.z = (u32)hu[4] | ((u32)hu[5] << 16);
        qh.w = (u32)hu[6] | ((u32)hu[7] << 16);
        Bhi4[nl * 4 + gg] = qh;
      }
    }
    __syncthreads();
    // ---- accumulate ----
    half8 bh = *reinterpret_cast<const half8*>(&Bhi4[nl2 * 4 + ggB]);
    half8 bl;
    if constexpr (!IN16) bl = *reinterpret_cast<const half8*>(&Blo4[nl2 * 4 + ggB]);
#pragma unroll
    for (int i = 0; i < 4; ++i) {
      if (i < imax && t >= (i >> 1) && t <= (i >> 1) + 6 + (i & 1)) {
        half8 a = *reinterpret_cast<const half8*>(&Ptab4[moff + 16 * i - 32 * t]);
        accH[i] = __builtin_amdgcn_mfma_f32_16x16x32_f16(a, bh, accH[i], 0, 0, 0);
        if constexpr (!IN16)
          accL[i] = __builtin_amdgcn_mfma_f32_16x16x32_f16(a, bl, accL[i], 0, 0, 0);
      }
    }
  }

  // ---- transposed store: out[t][c][r], lane holds 4 consecutive r ----
  const int c_out = n0 + 16 * wi + n16;
  const float SDE = 1.0f / 1024.0f;          // undo tap scale (exact pow2)
  if ((C % 64 == 0) || c_out < C) {
    if constexpr (!IN16) {                   // pass 1: f16 intermediate
      u16* of = (u16*)outv + fofs;
      for (int i = 0; i < imax; ++i) {
        const int r0 = m0 + 16 * i + 4 * g4;
        float v0 = (accH[i][0] + accL[i][0] * (1.0f / 2048.0f)) * SDE;
        float v1 = (accH[i][1] + accL[i][1] * (1.0f / 2048.0f)) * SDE;
        float v2 = (accH[i][2] + accL[i][2] * (1.0f / 2048.0f)) * SDE;
        float v3 = (accH[i][3] + accL[i][3] * (1.0f / 2048.0f)) * SDE;
        u16 h0 = __builtin_bit_cast(u16, (_Float16)v0);
        u16 h1 = __builtin_bit_cast(u16, (_Float16)v1);
        u16 h2 = __builtin_bit_cast(u16, (_Float16)v2);
        u16 h3 = __builtin_bit_cast(u16, (_Float16)v3);
        uint2 o; o.x = (u32)h0 | ((u32)h1 << 16); o.y = (u32)h2 | ((u32)h3 << 16);
        *(uint2*)(of + (size_t)c_out * R + r0) = o;
      }
    } else {                                 // pass 2: fp32 final output
      float* of = (float*)outv + fofs;
      for (int i = 0; i < imax; ++i) {
        const int r0 = m0 + 16 * i + 4 * g4;
        float4 o;
        o.x = accH[i][0] * SDE; o.y = accH[i][1] * SDE;
        o.z = accH[i][2] * SDE; o.w = accH[i][3] * SDE;
        *(float4*)(of + (size_t)c_out * R + r0) = o;
      }
    }
  }
}

// ============================================================================
// Fallback fp32 path (previous session's verified kernels, 472us) — used only
// if the harness workspace is too small for the f16 intermediate.
// ============================================================================
struct KTabZ { float v[272]; };
constexpr KTabZ make_ktz() {
  KTabZ t{};
  for (int i = 0; i < 272; ++i) t.v[i] = gaussk(i - 31);
  return t;
}
__device__ __constant__ KTabZ KTZ = make_ktz();

struct KTabE { float v[216]; };
constexpr KTabE make_kte() {
  KTabE t{};
  for (int i = 0; i < 216; ++i) t.v[i] = gaussk(i - 8);
  return t;
}
__device__ __constant__ KTabE KTE = make_kte();

__global__ __launch_bounds__(256, 4) void vpass(const float* __restrict__ x,
                                                float* __restrict__ y) {
  const int lid = blockIdx.x;
  const int xcd = lid & 7;
  const int s   = lid >> 3;
  const int f   = s / 34;
  const int r34 = s - 34 * f;
  const int t   = (f << 3) | xcd;
  const int wt  = r34 & 1;
  const int hc  = r34 >> 1;
  const int tid = threadIdx.x;
  const int w   = 2 * (wt * 256 + tid);
  const int h0  = hc * RV;
  if (w >= WWD) return;

  const float* xw = x + (size_t)t * (HH * WWD) + w;

  float ax[RV], ay[RV];
#pragma unroll
  for (int r = 0; r < RV; ++r) { ax[r] = 0.f; ay[r] = 0.f; }

#pragma unroll 8
  for (int bb = 0; bb < 232; ++bb) {
    const int h  = h0 + bb - PADC;
    const int hcl = (h < 0) ? 0 : ((h > HH - 1) ? HH - 1 : h);
    const float m = (h == hcl) ? 1.0f : 0.0f;
    float2 v = *(const float2*)(xw + (size_t)hcl * WWD);
    v.x *= m; v.y *= m;
    const float* kb = &KTZ.v[bb + 31];
#pragma unroll
    for (int r = 0; r < RV; ++r) {
      const float kk = kb[-r];
      ax[r] = fmaf(kk, v.x, ax[r]);
      ay[r] = fmaf(kk, v.y, ay[r]);
    }
  }

  float* yp = y + (size_t)t * (HH * WWD) + (size_t)h0 * WWD + w;
#pragma unroll
  for (int r = 0; r < RV; ++r) {
    float2 o; o.x = ax[r]; o.y = ay[r];
    *(float2*)(yp + (size_t)r * WWD) = o;
  }
}

__device__ __forceinline__ int swz(int q) { return q ^ ((q >> 3) & 1); }

__global__ __launch_bounds__(256, 4) void hpass(float* __restrict__ y) {
  __shared__ __align__(16) float4 row[2][292];
  const int tid = threadIdx.x;
  const int hh  = tid >> 7;
  const int lt  = tid & 127;
  float* yp = y + (size_t)(blockIdx.x * 2 + hh) * WWD;

  const float4 z4 = {0.f, 0.f, 0.f, 0.f};
  if (lt < 25) {
    row[hh][swz(lt)] = z4;
  } else if (lt >= 32 && lt < 57) {
    row[hh][swz(265 + lt - 32)] = z4;
  }
  if (lt < 120) {
    const int q0 = 25 + 2 * lt;
    row[hh][swz(q0)]     = *(const float4*)(yp + 8 * lt);
    row[hh][swz(q0 + 1)] = *(const float4*)(yp + 8 * lt + 4);
  }
  __syncthreads();

  if (lt < 120) {
    float a0=0.f,a1=0.f,a2=0.f,a3=0.f,a4=0.f,a5=0.f,a6=0.f,a7=0.f;
#pragma unroll 4
    for (int j = 0; j < 52; ++j) {
      const float4 v = row[hh][swz(2 * lt + j)];
      const float* kb = &KTE.v[4 * j + 8];
      {
        const float xv = v.x;
        a0 = fmaf(kb[0], xv, a0);  a1 = fmaf(kb[-1], xv, a1);
        a2 = fmaf(kb[-2], xv, a2); a3 = fmaf(kb[-3], xv, a3);
        a4 = fmaf(kb[-4], xv, a4); a5 = fmaf(kb[-5], xv, a5);
        a6 = fmaf(kb[-6], xv, a6); a7 = fmaf(kb[-7], xv, a7);
      }
      {
        const float xv = v.y;
        a0 = fmaf(kb[1], xv, a0);  a1 = fmaf(kb[0], xv, a1);
        a2 = fmaf(kb[-1], xv, a2); a3 = fmaf(kb[-2], xv, a3);
        a4 = fmaf(kb[-3], xv, a4); a5 = fmaf(kb[-4], xv, a5);
        a6 = fmaf(kb[-5], xv, a6); a7 = fmaf(kb[-6], xv, a7);
      }
      {
        const float xv = v.z;
        a0 = fmaf(kb[2], xv, a0);  a1 = fmaf(kb[1], xv, a1);
        a2 = fmaf(kb[0], xv, a2);  a3 = fmaf(kb[-1], xv, a3);
        a4 = fmaf(kb[-2], xv, a4); a5 = fmaf(kb[-3], xv, a5);
        a6 = fmaf(kb[-4], xv, a6); a7 = fmaf(kb[-5], xv, a7);
      }
      {
        const float xv = v.w;
        a0 = fmaf(kb[3], xv, a0);  a1 = fmaf(kb[2], xv, a1);
        a2 = fmaf(kb[1], xv, a2);  a3 = fmaf(kb[0], xv, a3);
        a4 = fmaf(kb[-1], xv, a4); a5 = fmaf(kb[-2], xv, a5);
        a6 = fmaf(kb[-3], xv, a6); a7 = fmaf(kb[-4], xv, a7);
      }
    }
    float4 o0; o0.x = a0; o0.y = a1; o0.z = a2; o0.w = a3;
    float4 o1; o1.x = a4; o1.y = a5; o1.z = a6; o1.w = a7;
    *(float4*)(yp + 8 * lt)     = o0;
    *(float4*)(yp + 8 * lt + 4) = o1;
  }
}

extern "C" void kernel_launch(void* const* d_in, const int* in_sizes, int n_in,
                              void* d_out, int out_size, void* d_ws, size_t ws_size,
                              hipStream_t stream) {
  const float* x = (const float*)d_in[0];
  float* out = (float*)d_out;
  (void)in_sizes; (void)n_in; (void)out_size;

  const size_t ws_need = (size_t)64 * HH * WWD * sizeof(u16);  // 66.8 MB
  if (d_ws != nullptr && ws_size >= ws_need) {
    u16* mid = (u16*)d_ws;
    // pass 1: vertical conv over H, fp32 -> f16, output transposed [t][w][h]
    gconvT<HH, WWD, false><<<dim3(8640), dim3(256), 0, stream>>>((const void*)x, (void*)mid);
    // pass 2: conv over W (leading dim of mid), f16 -> fp32, transposed back
    gconvT<WWD, HH, true ><<<dim3(8640), dim3(256), 0, stream>>>((const void*)mid, (void*)out);
  } else {
    vpass<<<dim3(2 * (HH / RV) * 64), dim3(256), 0, stream>>>(x, out);
    hpass<<<dim3(64 * HH / 2), dim3(256), 0, stream>>>(out);
  }
}

// Round 2
// 361.926 us; speedup vs baseline: 1.3302x; 1.3302x over previous
//
#include <hip/hip_runtime.h>

// ============================================================================
// GaussianBlur2D: separable 201-tap Gaussian (sigma=25, zero-pad), fp32 I/O.
// T=64, H=544, W=960.
//
// v2 MFMA path: both passes = banded-Toeplitz matmul on v_mfma_f32_16x16x32_f16.
//   pass1: fp32 in -> f16 intermediate (transposed [t][w][h] in d_ws), f16-RNE
//          input quantization only (lo-split dropped; error << 3.9e-3 tol).
//   pass2: f16 in -> fp32 out (transposed back).
// Structure per block: 128x128 output tile, 4 waves, acc 8x2 f32x4.
//   - reg-prefetch staging + double-buffered LDS, ONE barrier per 32-row K-step
//   - row clamp/mask is wave-uniform (scalar) -> skipped loads for pad rows
//   - A-fragments: only 15 distinct per lane (u=i-2t in [-13,1]); prebuilt in
//     lane-indexed LDS PF[15][64] -> conflict-free 16B reads (replaces the
//     5-way-conflicted sliding Ptab of r1)
//   - B LDS swizzle g^((col>>1)&3): reads conflict-free, writes 2-way (free)
// Fallback: if ws_size < 67MB, previous verified fp32 vpass/hpass (472us).
// ============================================================================

typedef _Float16 half8 __attribute__((ext_vector_type(8)));
typedef float    f32x4 __attribute__((ext_vector_type(4)));
typedef unsigned short u16;
typedef unsigned int   u32;

#define HH   544
#define WWD  960
#define PADC 100
#define RV   32

// ---- compile-time Gaussian (double Taylor exp, rounded to f32) ----
constexpr double cexp_taylor(double x) {
  double term = 1.0, sum = 1.0;
  for (int n = 1; n < 120; ++n) { term *= x / n; sum += term; }
  return sum;
}
constexpr float gaussk(int k) {            // tap k in [0,200] -> g(k-100), else 0
  if (k < 0 || k > 200) return 0.0f;
  double r = (double)(k - PADC);
  return (float)(cexp_taylor(-(r * r) / (2.0 * 25.0 * 25.0))
                 / (25.0 * 2.5066282746310002));
}

// zero-padded tap table: G0.v[v] = gaussk(v - 40), v in [0,288)
struct G0T { float v[288]; };
constexpr G0T make_g0() {
  G0T t{};
  for (int i = 0; i < 288; ++i) t.v[i] = gaussk(i - 40);
  return t;
}
__device__ __constant__ G0T G0 = make_g0();

__device__ __forceinline__ u16 f16u(float x) {
  return __builtin_bit_cast(u16, (_Float16)x);   // RNE
}

// ============================================================================
// Transposing banded conv, 128x128 tile:
//   in : 64 frames [R][C] row-major, conv along R (201 taps, zero-pad)
//   out: 64 frames [C][R]   out[t][c][r] = sum_b g(b) in[t][r+b-100][c]
// A-frag (taps): lane nl holds A[m=nl&15][k=8*(nl>>4)+b] =
//   1024*gaussk(m + 200 + 16u - k), u = i - 2t  -> PF[u+13][nl]
// B-frag (data): lane holds col=(nl&15)+16nt+32wv, k-group nl>>4 (8 contig k)
// C/D: col=lane&15, row=4*(lane>>4)+reg (verified r1).
// ============================================================================
template<int R, int C, bool IN16>
__global__ __launch_bounds__(256, 3) void gconv2(const void* __restrict__ inv,
                                                 void* __restrict__ outv) {
  constexpr int MB  = (R + 127) / 128;
  constexpr int NB  = (C + 127) / 128;
  constexpr int BPF = MB * NB;

  const int lid = blockIdx.x;
  const int xcd = lid & 7;                 // frame -> XCD affinity
  const int s   = lid >> 3;
  const int f   = s / BPF;
  const int rb_ = s - f * BPF;
  const int tf  = (f << 3) | xcd;          // frame 0..63
  const int mb  = rb_ / NB;
  const int nb  = rb_ - mb * NB;
  const int m0  = mb * 128, n0 = nb * 128;
  const int imax = ((R - m0) >> 4) < 8 ? ((R - m0) >> 4) : 8;
  const int Tblk = ((16 * imax + 215) >> 5) + 1;   // 32-row K-steps

  const int tid = threadIdx.x;
  const size_t fofs = (size_t)tf * R * C;

  __shared__ uint4 PF[15][64];             // tap A-frags, lane-indexed
  __shared__ uint4 Bbuf[2][512];           // double-buffered data tile

  // ---- build tap-fragment table (once per block) ----
  for (int E = tid; E < 960; E += 256) {
    const int le = E & 63, uq = E >> 6;
    const int bas = (le & 15) - 8 * (le >> 4) + 16 * uq + 32;  // G0 idx at b=0
    u32 w[4];
#pragma unroll
    for (int p = 0; p < 4; ++p) {
      const u16 h0 = f16u(G0.v[bas - 2 * p] * 1024.0f);
      const u16 h1 = f16u(G0.v[bas - 2 * p - 1] * 1024.0f);
      w[p] = (u32)h0 | ((u32)h1 << 16);
    }
    uint4 q; q.x = w[0]; q.y = w[1]; q.z = w[2]; q.w = w[3];
    PF[uq][le] = q;
  }

  const int nl   = tid & 63;
  const int wv   = tid >> 6;
  const int n16  = nl & 15, g4 = nl >> 4;
  const int cc0  = n0 + 2 * nl;            // this thread's staged col pair
  const int ccl  = cc0 < C - 2 ? cc0 : C - 2;
  const int kb0  = m0 - PADC;
  const int swW  = wv ^ (nl & 3);          // write-side swizzled group
  const int ggB  = g4 ^ ((n16 >> 1) & 3);  // read-side swizzled group
  const int colA = 32 * wv + n16;          // wave's first output col (local)

  const float* inF = (const float*)inv + fofs + ccl;
  const u16*   inH = (const u16*)inv + fofs + ccl;

  float2 ldf[8];
  u32    ldh[8];

  auto LOADREGS = [&](int t) {
    const int rbase = kb0 + 32 * t + 8 * wv;
#pragma unroll
    for (int j = 0; j < 8; ++j) {
      const int rr = rbase + j;            // wave-uniform -> scalar branch
      const bool ok = (rr >= 0) && (rr < R);
      if constexpr (!IN16) {
        ldf[j] = ok ? *(const float2*)(inF + (size_t)rr * C)
                    : make_float2(0.f, 0.f);
      } else {
        ldh[j] = ok ? *(const u32*)(inH + (size_t)rr * C) : 0u;
      }
    }
  };

  f32x4 acc[8][2];
#pragma unroll
  for (int i = 0; i < 8; ++i) {
    acc[i][0] = (f32x4){0.f, 0.f, 0.f, 0.f};
    acc[i][1] = (f32x4){0.f, 0.f, 0.f, 0.f};
  }

  LOADREGS(0);

  for (int t = 0; t < Tblk; ++t) {
    // ---- pack regs(t) -> two col-major uint4 (col 2nl, col 2nl+1) ----
    uint4 qx, qy;
    if constexpr (!IN16) {
      u32 px[4], py[4];
#pragma unroll
      for (int p = 0; p < 4; ++p) {
        const float2 v0 = ldf[2 * p], v1 = ldf[2 * p + 1];
        px[p] = (u32)f16u(v0.x) | ((u32)f16u(v1.x) << 16);
        py[p] = (u32)f16u(v0.y) | ((u32)f16u(v1.y) << 16);
      }
      qx.x = px[0]; qx.y = px[1]; qx.z = px[2]; qx.w = px[3];
      qy.x = py[0]; qy.y = py[1]; qy.z = py[2]; qy.w = py[3];
    } else {
      qx.x = (ldh[0] & 0xffffu) | (ldh[1] << 16);
      qx.y = (ldh[2] & 0xffffu) | (ldh[3] << 16);
      qx.z = (ldh[4] & 0xffffu) | (ldh[5] << 16);
      qx.w = (ldh[6] & 0xffffu) | (ldh[7] << 16);
      qy.x = (ldh[0] >> 16) | (ldh[1] & 0xffff0000u);
      qy.y = (ldh[2] >> 16) | (ldh[3] & 0xffff0000u);
      qy.z = (ldh[4] >> 16) | (ldh[5] & 0xffff0000u);
      qy.w = (ldh[6] >> 16) | (ldh[7] & 0xffff0000u);
    }

    // ---- issue next step's global loads (latency hides under barrier+MFMA)
    if (t + 1 < Tblk) LOADREGS(t + 1);

    // ---- stage to LDS buf[t&1]; writes 2-way conflict (free) ----
    Bbuf[t & 1][(2 * nl) * 4 + swW]     = qx;
    Bbuf[t & 1][(2 * nl + 1) * 4 + swW] = qy;
    __syncthreads();                       // one barrier/step (2 bufs: safe)

    // ---- compute: 2 n-tiles per wave, conflict-free frag reads ----
    const half8 b0 = *reinterpret_cast<const half8*>(&Bbuf[t & 1][colA * 4 + ggB]);
    const half8 b1 = *reinterpret_cast<const half8*>(&Bbuf[t & 1][(colA + 16) * 4 + ggB]);
#pragma unroll
    for (int i = 0; i < 8; ++i) {
      const int tlo = i >> 1;
      if (i < imax && t >= tlo && t <= tlo + 6 + (i & 1)) {
        const half8 a = *reinterpret_cast<const half8*>(&PF[i - 2 * t + 13][nl]);
        acc[i][0] = __builtin_amdgcn_mfma_f32_16x16x32_f16(a, b0, acc[i][0], 0, 0, 0);
        acc[i][1] = __builtin_amdgcn_mfma_f32_16x16x32_f16(a, b1, acc[i][1], 0, 0, 0);
      }
    }
  }

  // ---- transposed store: out[t][c][r]; lane holds 4 consecutive r ----
  const float SDE = 1.0f / 1024.0f;        // undo tap scale (exact pow2)
#pragma unroll
  for (int nt = 0; nt < 2; ++nt) {
    const int c_out = n0 + colA + 16 * nt;
    if (((C & 127) == 0) || (c_out < C)) {
      if constexpr (!IN16) {               // pass 1: f16 intermediate
        u16* of = (u16*)outv + fofs + (size_t)c_out * R;
#pragma unroll
        for (int i = 0; i < 8; ++i) {
          if (i < imax) {
            const int r0 = m0 + 16 * i + 4 * g4;
            uint2 o;
            o.x = (u32)f16u(acc[i][nt][0] * SDE) | ((u32)f16u(acc[i][nt][1] * SDE) << 16);
            o.y = (u32)f16u(acc[i][nt][2] * SDE) | ((u32)f16u(acc[i][nt][3] * SDE) << 16);
            *(uint2*)(of + r0) = o;
          }
        }
      } else {                             // pass 2: fp32 final output
        float* of = (float*)outv + fofs + (size_t)c_out * R;
#pragma unroll
        for (int i = 0; i < 8; ++i) {
          if (i < imax) {
            const int r0 = m0 + 16 * i + 4 * g4;
            float4 o;
            o.x = acc[i][nt][0] * SDE; o.y = acc[i][nt][1] * SDE;
            o.z = acc[i][nt][2] * SDE; o.w = acc[i][nt][3] * SDE;
            *(float4*)(of + r0) = o;
          }
        }
      }
    }
  }
}

// ============================================================================
// Fallback fp32 path (verified, 472us) — only if workspace too small.
// ============================================================================
struct KTabZ { float v[272]; };
constexpr KTabZ make_ktz() {
  KTabZ t{};
  for (int i = 0; i < 272; ++i) t.v[i] = gaussk(i - 31);
  return t;
}
__device__ __constant__ KTabZ KTZ = make_ktz();

struct KTabE { float v[216]; };
constexpr KTabE make_kte() {
  KTabE t{};
  for (int i = 0; i < 216; ++i) t.v[i] = gaussk(i - 8);
  return t;
}
__device__ __constant__ KTabE KTE = make_kte();

__global__ __launch_bounds__(256, 4) void vpass(const float* __restrict__ x,
                                                float* __restrict__ y) {
  const int lid = blockIdx.x;
  const int xcd = lid & 7;
  const int s   = lid >> 3;
  const int f   = s / 34;
  const int r34 = s - 34 * f;
  const int t   = (f << 3) | xcd;
  const int wt  = r34 & 1;
  const int hc  = r34 >> 1;
  const int tid = threadIdx.x;
  const int w   = 2 * (wt * 256 + tid);
  const int h0  = hc * RV;
  if (w >= WWD) return;

  const float* xw = x + (size_t)t * (HH * WWD) + w;

  float ax[RV], ay[RV];
#pragma unroll
  for (int r = 0; r < RV; ++r) { ax[r] = 0.f; ay[r] = 0.f; }

#pragma unroll 8
  for (int bb = 0; bb < 232; ++bb) {
    const int h  = h0 + bb - PADC;
    const int hcl = (h < 0) ? 0 : ((h > HH - 1) ? HH - 1 : h);
    const float m = (h == hcl) ? 1.0f : 0.0f;
    float2 v = *(const float2*)(xw + (size_t)hcl * WWD);
    v.x *= m; v.y *= m;
    const float* kb = &KTZ.v[bb + 31];
#pragma unroll
    for (int r = 0; r < RV; ++r) {
      const float kk = kb[-r];
      ax[r] = fmaf(kk, v.x, ax[r]);
      ay[r] = fmaf(kk, v.y, ay[r]);
    }
  }

  float* yp = y + (size_t)t * (HH * WWD) + (size_t)h0 * WWD + w;
#pragma unroll
  for (int r = 0; r < RV; ++r) {
    float2 o; o.x = ax[r]; o.y = ay[r];
    *(float2*)(yp + (size_t)r * WWD) = o;
  }
}

__device__ __forceinline__ int swz(int q) { return q ^ ((q >> 3) & 1); }

__global__ __launch_bounds__(256, 4) void hpass(float* __restrict__ y) {
  __shared__ __align__(16) float4 row[2][292];
  const int tid = threadIdx.x;
  const int hh  = tid >> 7;
  const int lt  = tid & 127;
  float* yp = y + (size_t)(blockIdx.x * 2 + hh) * WWD;

  const float4 z4 = {0.f, 0.f, 0.f, 0.f};
  if (lt < 25) {
    row[hh][swz(lt)] = z4;
  } else if (lt >= 32 && lt < 57) {
    row[hh][swz(265 + lt - 32)] = z4;
  }
  if (lt < 120) {
    const int q0 = 25 + 2 * lt;
    row[hh][swz(q0)]     = *(const float4*)(yp + 8 * lt);
    row[hh][swz(q0 + 1)] = *(const float4*)(yp + 8 * lt + 4);
  }
  __syncthreads();

  if (lt < 120) {
    float a0=0.f,a1=0.f,a2=0.f,a3=0.f,a4=0.f,a5=0.f,a6=0.f,a7=0.f;
#pragma unroll 4
    for (int j = 0; j < 52; ++j) {
      const float4 v = row[hh][swz(2 * lt + j)];
      const float* kb = &KTE.v[4 * j + 8];
      {
        const float xv = v.x;
        a0 = fmaf(kb[0], xv, a0);  a1 = fmaf(kb[-1], xv, a1);
        a2 = fmaf(kb[-2], xv, a2); a3 = fmaf(kb[-3], xv, a3);
        a4 = fmaf(kb[-4], xv, a4); a5 = fmaf(kb[-5], xv, a5);
        a6 = fmaf(kb[-6], xv, a6); a7 = fmaf(kb[-7], xv, a7);
      }
      {
        const float xv = v.y;
        a0 = fmaf(kb[1], xv, a0);  a1 = fmaf(kb[0], xv, a1);
        a2 = fmaf(kb[-1], xv, a2); a3 = fmaf(kb[-2], xv, a3);
        a4 = fmaf(kb[-3], xv, a4); a5 = fmaf(kb[-4], xv, a5);
        a6 = fmaf(kb[-5], xv, a6); a7 = fmaf(kb[-6], xv, a7);
      }
      {
        const float xv = v.z;
        a0 = fmaf(kb[2], xv, a0);  a1 = fmaf(kb[1], xv, a1);
        a2 = fmaf(kb[0], xv, a2);  a3 = fmaf(kb[-1], xv, a3);
        a4 = fmaf(kb[-2], xv, a4); a5 = fmaf(kb[-3], xv, a5);
        a6 = fmaf(kb[-4], xv, a6); a7 = fmaf(kb[-5], xv, a7);
      }
      {
        const float xv = v.w;
        a0 = fmaf(kb[3], xv, a0);  a1 = fmaf(kb[2], xv, a1);
        a2 = fmaf(kb[1], xv, a2);  a3 = fmaf(kb[0], xv, a3);
        a4 = fmaf(kb[-1], xv, a4); a5 = fmaf(kb[-2], xv, a5);
        a6 = fmaf(kb[-3], xv, a6); a7 = fmaf(kb[-4], xv, a7);
      }
    }
    float4 o0; o0.x = a0; o0.y = a1; o0.z = a2; o0.w = a3;
    float4 o1; o1.x = a4; o1.y = a5; o1.z = a6; o1.w = a7;
    *(float4*)(yp + 8 * lt)     = o0;
    *(float4*)(yp + 8 * lt + 4) = o1;
  }
}

extern "C" void kernel_launch(void* const* d_in, const int* in_sizes, int n_in,
                              void* d_out, int out_size, void* d_ws, size_t ws_size,
                              hipStream_t stream) {
  const float* x = (const float*)d_in[0];
  float* out = (float*)d_out;
  (void)in_sizes; (void)n_in; (void)out_size;

  const size_t ws_need = (size_t)64 * HH * WWD * sizeof(u16);  // 66.8 MB
  if (d_ws != nullptr && ws_size >= ws_need) {
    u16* mid = (u16*)d_ws;
    // pass 1: conv over H, fp32 -> f16, output transposed [t][w][h]
    gconv2<HH, WWD, false><<<dim3(2560), dim3(256), 0, stream>>>((const void*)x, (void*)mid);
    // pass 2: conv over W (leading dim of mid), f16 -> fp32, transposed back
    gconv2<WWD, HH, true ><<<dim3(2560), dim3(256), 0, stream>>>((const void*)mid, (void*)out);
  } else {
    vpass<<<dim3(2 * (HH / RV) * 64), dim3(256), 0, stream>>>(x, out);
    hpass<<<dim3(64 * HH / 2), dim3(256), 0, stream>>>(out);
  }
}

// Round 3
// 352.405 us; speedup vs baseline: 1.3662x; 1.0270x over previous
//
#include <hip/hip_runtime.h>

// ============================================================================
// GaussianBlur2D: separable 201-tap Gaussian (sigma=25, zero-pad), fp32 I/O.
// T=64, H=544, W=960.
//
// v3 MFMA path: banded-Toeplitz matmul on v_mfma_f32_16x16x32_f16, both passes.
//   pass1: fp32 in -> f16 intermediate (transposed [t][w][h] in d_ws)
//   pass2: f16 in -> fp32 out (transposed back). Numerics identical to v2.
// v3 changes (sync structure only):
//   - RAW s_barrier + counted waits: __syncthreads() drains vmcnt(0) at every
//     barrier (compiler-enforced), serializing each K-step on full HBM latency
//     -> replace with asm lgkmcnt(0) + __builtin_amdgcn_s_barrier() +
//     sched_barrier(0). Prefetched global loads now survive across barriers;
//     compiler emits counted vmcnt at the consuming pack (T3/T4 pattern).
//   - 2-deep register pipeline: named reg sets A/B, hand-pipelined 2-step loop
//     (no runtime indexing), consume set issued 2 steps earlier.
//   - __launch_bounds__(256,4): 4 blocks/CU (LDS 31.7KB, VGPR<=128).
//   - skip K-steps whose staged 32 rows are entirely zero-pad (t_lo/t_hi).
//   - s_setprio(1) around MFMA cluster (independent blocks -> role diversity).
// Fallback: if ws_size < 67MB, previous verified fp32 vpass/hpass (472us).
// ============================================================================

typedef _Float16 half8 __attribute__((ext_vector_type(8)));
typedef float    f32x4 __attribute__((ext_vector_type(4)));
typedef unsigned short u16;
typedef unsigned int   u32;

#define HH   544
#define WWD  960
#define PADC 100
#define RV   32

// ---- compile-time Gaussian (double Taylor exp, rounded to f32) ----
constexpr double cexp_taylor(double x) {
  double term = 1.0, sum = 1.0;
  for (int n = 1; n < 120; ++n) { term *= x / n; sum += term; }
  return sum;
}
constexpr float gaussk(int k) {            // tap k in [0,200] -> g(k-100), else 0
  if (k < 0 || k > 200) return 0.0f;
  double r = (double)(k - PADC);
  return (float)(cexp_taylor(-(r * r) / (2.0 * 25.0 * 25.0))
                 / (25.0 * 2.5066282746310002));
}

// zero-padded tap table: G0.v[v] = gaussk(v - 40), v in [0,288)
struct G0T { float v[288]; };
constexpr G0T make_g0() {
  G0T t{};
  for (int i = 0; i < 288; ++i) t.v[i] = gaussk(i - 40);
  return t;
}
__device__ __constant__ G0T G0 = make_g0();

__device__ __forceinline__ u16 f16u(float x) {
  return __builtin_bit_cast(u16, (_Float16)x);   // RNE
}

// ============================================================================
// Transposing banded conv, 128x128 tile (layouts verified r1/r2):
//   in : 64 frames [R][C] row-major, conv along R (201 taps, zero-pad)
//   out: 64 frames [C][R]   out[t][c][r] = sum_b g(b) in[t][r+b-100][c]
// A-frag (taps): PF[u+13][lane], u = i - 2t in [-13,1]
// B-frag (data): lane holds col=(nl&15)+16nt+32wv, k-group nl>>4
// C/D: col=lane&15, row=4*(lane>>4)+reg
// ============================================================================
template<int R, int C, bool IN16>
__global__ __launch_bounds__(256, 4) void gconv3(const void* __restrict__ inv,
                                                 void* __restrict__ outv) {
  constexpr int MB  = (R + 127) / 128;
  constexpr int NB  = (C + 127) / 128;
  constexpr int BPF = MB * NB;

  const int lid = blockIdx.x;
  const int xcd = lid & 7;                 // frame -> XCD affinity
  const int s   = lid >> 3;
  const int f   = s / BPF;
  const int rb_ = s - f * BPF;
  const int tf  = (f << 3) | xcd;          // frame 0..63
  const int mb  = rb_ / NB;
  const int nb  = rb_ - mb * NB;
  const int m0  = mb * 128, n0 = nb * 128;
  const int imax = ((R - m0) >> 4) < 8 ? ((R - m0) >> 4) : 8;
  const int Tblk = ((16 * imax + 215) >> 5) + 1;   // 32-row K-steps (band)

  // skip K-steps whose 32 staged rows are entirely outside [0,R) (pure pad)
  const int t_lo = (m0 >= 69) ? 0 : ((100 - m0) >> 5);          // ceil((69-m0)/32)
  int t_hi = (R + 99 - m0) / 32 + 1;
  if (t_hi > Tblk) t_hi = Tblk;

  const int tid = threadIdx.x;
  const size_t fofs = (size_t)tf * R * C;

  __shared__ uint4 PF[15][64];             // tap A-frags, lane-indexed
  __shared__ uint4 Bbuf[2][512];           // double-buffered data tile

  // ---- build tap-fragment table (once per block) ----
  for (int E = tid; E < 960; E += 256) {
    const int le = E & 63, uq = E >> 6;
    const int bas = (le & 15) - 8 * (le >> 4) + 16 * uq + 32;  // G0 idx at b=0
    u32 w[4];
#pragma unroll
    for (int p = 0; p < 4; ++p) {
      const u16 h0 = f16u(G0.v[bas - 2 * p] * 1024.0f);
      const u16 h1 = f16u(G0.v[bas - 2 * p - 1] * 1024.0f);
      w[p] = (u32)h0 | ((u32)h1 << 16);
    }
    uint4 q; q.x = w[0]; q.y = w[1]; q.z = w[2]; q.w = w[3];
    PF[uq][le] = q;
  }

  const int nl   = tid & 63;
  const int wv   = tid >> 6;
  const int n16  = nl & 15, g4 = nl >> 4;
  const int cc0  = n0 + 2 * nl;            // this thread's staged col pair
  const int ccl  = cc0 < C - 2 ? cc0 : C - 2;
  const int kb0  = m0 - PADC;
  const int swW  = wv ^ (nl & 3);          // write-side swizzled group
  const int ggB  = g4 ^ ((n16 >> 1) & 3);  // read-side swizzled group
  const int colA = 32 * wv + n16;          // wave's first output col (local)

  const float* inF = (const float*)inv + fofs + ccl;
  const u16*   inH = (const u16*)inv + fofs + ccl;

  // two named prefetch register sets (2-deep pipeline, static indexing only)
  float2 lfA[8], lfB[8];
  u32    lhA[8], lhB[8];

  auto loadregs = [&](int t, float2 (&lf)[8], u32 (&lh)[8]) {
    const int rbase = kb0 + 32 * t + 8 * wv;
#pragma unroll
    for (int j = 0; j < 8; ++j) {
      const int rr = rbase + j;            // wave-uniform -> scalar branch
      const bool ok = (rr >= 0) && (rr < R);
      if constexpr (!IN16) {
        lf[j] = ok ? *(const float2*)(inF + (size_t)rr * C)
                   : make_float2(0.f, 0.f);
      } else {
        lh[j] = ok ? *(const u32*)(inH + (size_t)rr * C) : 0u;
      }
    }
    (void)lf; (void)lh;
  };

  f32x4 acc[8][2];
#pragma unroll
  for (int i = 0; i < 8; ++i) {
    acc[i][0] = (f32x4){0.f, 0.f, 0.f, 0.f};
    acc[i][1] = (f32x4){0.f, 0.f, 0.f, 0.f};
  }

  auto step = [&](int t, float2 (&lf)[8], u32 (&lh)[8]) {
    // ---- pack regs(t) -> two col-major uint4 (compiler waits counted vmcnt)
    uint4 qx, qy;
    if constexpr (!IN16) {
      u32 px[4], py[4];
#pragma unroll
      for (int p = 0; p < 4; ++p) {
        const float2 v0 = lf[2 * p], v1 = lf[2 * p + 1];
        px[p] = (u32)f16u(v0.x) | ((u32)f16u(v1.x) << 16);
        py[p] = (u32)f16u(v0.y) | ((u32)f16u(v1.y) << 16);
      }
      qx.x = px[0]; qx.y = px[1]; qx.z = px[2]; qx.w = px[3];
      qy.x = py[0]; qy.y = py[1]; qy.z = py[2]; qy.w = py[3];
    } else {
      qx.x = (lh[0] & 0xffffu) | (lh[1] << 16);
      qx.y = (lh[2] & 0xffffu) | (lh[3] << 16);
      qx.z = (lh[4] & 0xffffu) | (lh[5] << 16);
      qx.w = (lh[6] & 0xffffu) | (lh[7] << 16);
      qy.x = (lh[0] >> 16) | (lh[1] & 0xffff0000u);
      qy.y = (lh[2] >> 16) | (lh[3] & 0xffff0000u);
      qy.z = (lh[4] >> 16) | (lh[5] & 0xffff0000u);
      qy.w = (lh[6] >> 16) | (lh[7] & 0xffff0000u);
    }

    // ---- issue loads for t+2 into the same set (in flight across barriers)
    if (t + 2 < t_hi) loadregs(t + 2, lf, lh);

    // ---- stage to LDS buf[t&1] ----
    Bbuf[t & 1][(2 * nl) * 4 + swW]     = qx;
    Bbuf[t & 1][(2 * nl + 1) * 4 + swW] = qy;

    // ---- raw barrier: ds_writes visible, global loads NOT drained ----
    asm volatile("s_waitcnt lgkmcnt(0)" ::: "memory");
    __builtin_amdgcn_s_barrier();
    __builtin_amdgcn_sched_barrier(0);

    // ---- compute: 2 n-tiles per wave, conflict-free frag reads ----
    const half8 b0 = *reinterpret_cast<const half8*>(&Bbuf[t & 1][colA * 4 + ggB]);
    const half8 b1 = *reinterpret_cast<const half8*>(&Bbuf[t & 1][(colA + 16) * 4 + ggB]);
    __builtin_amdgcn_s_setprio(1);
#pragma unroll
    for (int i = 0; i < 8; ++i) {
      const int tlo = i >> 1;
      if (i < imax && t >= tlo && t <= tlo + 6 + (i & 1)) {
        const half8 a = *reinterpret_cast<const half8*>(&PF[i - 2 * t + 13][nl]);
        acc[i][0] = __builtin_amdgcn_mfma_f32_16x16x32_f16(a, b0, acc[i][0], 0, 0, 0);
        acc[i][1] = __builtin_amdgcn_mfma_f32_16x16x32_f16(a, b1, acc[i][1], 0, 0, 0);
      }
    }
    __builtin_amdgcn_s_setprio(0);
  };

  // ---- software-pipelined main loop (2-deep prefetch, 1 barrier/step) ----
  loadregs(t_lo, lfA, lhA);
  if (t_lo + 1 < t_hi) loadregs(t_lo + 1, lfB, lhB);

  for (int t = t_lo; t < t_hi; t += 2) {
    step(t, lfA, lhA);
    if (t + 1 < t_hi) step(t + 1, lfB, lhB);
  }

  // ---- transposed store: out[t][c][r]; lane holds 4 consecutive r ----
  const float SDE = 1.0f / 1024.0f;        // undo tap scale (exact pow2)
#pragma unroll
  for (int nt = 0; nt < 2; ++nt) {
    const int c_out = n0 + colA + 16 * nt;
    if (((C & 127) == 0) || (c_out < C)) {
      if constexpr (!IN16) {               // pass 1: f16 intermediate
        u16* of = (u16*)outv + fofs + (size_t)c_out * R;
#pragma unroll
        for (int i = 0; i < 8; ++i) {
          if (i < imax) {
            const int r0 = m0 + 16 * i + 4 * g4;
            uint2 o;
            o.x = (u32)f16u(acc[i][nt][0] * SDE) | ((u32)f16u(acc[i][nt][1] * SDE) << 16);
            o.y = (u32)f16u(acc[i][nt][2] * SDE) | ((u32)f16u(acc[i][nt][3] * SDE) << 16);
            *(uint2*)(of + r0) = o;
          }
        }
      } else {                             // pass 2: fp32 final output
        float* of = (float*)outv + fofs + (size_t)c_out * R;
#pragma unroll
        for (int i = 0; i < 8; ++i) {
          if (i < imax) {
            const int r0 = m0 + 16 * i + 4 * g4;
            float4 o;
            o.x = acc[i][nt][0] * SDE; o.y = acc[i][nt][1] * SDE;
            o.z = acc[i][nt][2] * SDE; o.w = acc[i][nt][3] * SDE;
            *(float4*)(of + r0) = o;
          }
        }
      }
    }
  }
}

// ============================================================================
// Fallback fp32 path (verified, 472us) — only if workspace too small.
// ============================================================================
struct KTabZ { float v[272]; };
constexpr KTabZ make_ktz() {
  KTabZ t{};
  for (int i = 0; i < 272; ++i) t.v[i] = gaussk(i - 31);
  return t;
}
__device__ __constant__ KTabZ KTZ = make_ktz();

struct KTabE { float v[216]; };
constexpr KTabE make_kte() {
  KTabE t{};
  for (int i = 0; i < 216; ++i) t.v[i] = gaussk(i - 8);
  return t;
}
__device__ __constant__ KTabE KTE = make_kte();

__global__ __launch_bounds__(256, 4) void vpass(const float* __restrict__ x,
                                                float* __restrict__ y) {
  const int lid = blockIdx.x;
  const int xcd = lid & 7;
  const int s   = lid >> 3;
  const int f   = s / 34;
  const int r34 = s - 34 * f;
  const int t   = (f << 3) | xcd;
  const int wt  = r34 & 1;
  const int hc  = r34 >> 1;
  const int tid = threadIdx.x;
  const int w   = 2 * (wt * 256 + tid);
  const int h0  = hc * RV;
  if (w >= WWD) return;

  const float* xw = x + (size_t)t * (HH * WWD) + w;

  float ax[RV], ay[RV];
#pragma unroll
  for (int r = 0; r < RV; ++r) { ax[r] = 0.f; ay[r] = 0.f; }

#pragma unroll 8
  for (int bb = 0; bb < 232; ++bb) {
    const int h  = h0 + bb - PADC;
    const int hcl = (h < 0) ? 0 : ((h > HH - 1) ? HH - 1 : h);
    const float m = (h == hcl) ? 1.0f : 0.0f;
    float2 v = *(const float2*)(xw + (size_t)hcl * WWD);
    v.x *= m; v.y *= m;
    const float* kb = &KTZ.v[bb + 31];
#pragma unroll
    for (int r = 0; r < RV; ++r) {
      const float kk = kb[-r];
      ax[r] = fmaf(kk, v.x, ax[r]);
      ay[r] = fmaf(kk, v.y, ay[r]);
    }
  }

  float* yp = y + (size_t)t * (HH * WWD) + (size_t)h0 * WWD + w;
#pragma unroll
  for (int r = 0; r < RV; ++r) {
    float2 o; o.x = ax[r]; o.y = ay[r];
    *(float2*)(yp + (size_t)r * WWD) = o;
  }
}

__device__ __forceinline__ int swz(int q) { return q ^ ((q >> 3) & 1); }

__global__ __launch_bounds__(256, 4) void hpass(float* __restrict__ y) {
  __shared__ __align__(16) float4 row[2][292];
  const int tid = threadIdx.x;
  const int hh  = tid >> 7;
  const int lt  = tid & 127;
  float* yp = y + (size_t)(blockIdx.x * 2 + hh) * WWD;

  const float4 z4 = {0.f, 0.f, 0.f, 0.f};
  if (lt < 25) {
    row[hh][swz(lt)] = z4;
  } else if (lt >= 32 && lt < 57) {
    row[hh][swz(265 + lt - 32)] = z4;
  }
  if (lt < 120) {
    const int q0 = 25 + 2 * lt;
    row[hh][swz(q0)]     = *(const float4*)(yp + 8 * lt);
    row[hh][swz(q0 + 1)] = *(const float4*)(yp + 8 * lt + 4);
  }
  __syncthreads();

  if (lt < 120) {
    float a0=0.f,a1=0.f,a2=0.f,a3=0.f,a4=0.f,a5=0.f,a6=0.f,a7=0.f;
#pragma unroll 4
    for (int j = 0; j < 52; ++j) {
      const float4 v = row[hh][swz(2 * lt + j)];
      const float* kb = &KTE.v[4 * j + 8];
      {
        const float xv = v.x;
        a0 = fmaf(kb[0], xv, a0);  a1 = fmaf(kb[-1], xv, a1);
        a2 = fmaf(kb[-2], xv, a2); a3 = fmaf(kb[-3], xv, a3);
        a4 = fmaf(kb[-4], xv, a4); a5 = fmaf(kb[-5], xv, a5);
        a6 = fmaf(kb[-6], xv, a6); a7 = fmaf(kb[-7], xv, a7);
      }
      {
        const float xv = v.y;
        a0 = fmaf(kb[1], xv, a0);  a1 = fmaf(kb[0], xv, a1);
        a2 = fmaf(kb[-1], xv, a2); a3 = fmaf(kb[-2], xv, a3);
        a4 = fmaf(kb[-3], xv, a4); a5 = fmaf(kb[-4], xv, a5);
        a6 = fmaf(kb[-5], xv, a6); a7 = fmaf(kb[-6], xv, a7);
      }
      {
        const float xv = v.z;
        a0 = fmaf(kb[2], xv, a0);  a1 = fmaf(kb[1], xv, a1);
        a2 = fmaf(kb[0], xv, a2);  a3 = fmaf(kb[-1], xv, a3);
        a4 = fmaf(kb[-2], xv, a4); a5 = fmaf(kb[-3], xv, a5);
        a6 = fmaf(kb[-4], xv, a6); a7 = fmaf(kb[-5], xv, a7);
      }
      {
        const float xv = v.w;
        a0 = fmaf(kb[3], xv, a0);  a1 = fmaf(kb[2], xv, a1);
        a2 = fmaf(kb[1], xv, a2);  a3 = fmaf(kb[0], xv, a3);
        a4 = fmaf(kb[-1], xv, a4); a5 = fmaf(kb[-2], xv, a5);
        a6 = fmaf(kb[-3], xv, a6); a7 = fmaf(kb[-4], xv, a7);
      }
    }
    float4 o0; o0.x = a0; o0.y = a1; o0.z = a2; o0.w = a3;
    float4 o1; o1.x = a4; o1.y = a5; o1.z = a6; o1.w = a7;
    *(float4*)(yp + 8 * lt)     = o0;
    *(float4*)(yp + 8 * lt + 4) = o1;
  }
}

extern "C" void kernel_launch(void* const* d_in, const int* in_sizes, int n_in,
                              void* d_out, int out_size, void* d_ws, size_t ws_size,
                              hipStream_t stream) {
  const float* x = (const float*)d_in[0];
  float* out = (float*)d_out;
  (void)in_sizes; (void)n_in; (void)out_size;

  const size_t ws_need = (size_t)64 * HH * WWD * sizeof(u16);  // 66.8 MB
  if (d_ws != nullptr && ws_size >= ws_need) {
    u16* mid = (u16*)d_ws;
    // pass 1: conv over H, fp32 -> f16, output transposed [t][w][h]
    gconv3<HH, WWD, false><<<dim3(2560), dim3(256), 0, stream>>>((const void*)x, (void*)mid);
    // pass 2: conv over W (leading dim of mid), f16 -> fp32, transposed back
    gconv3<WWD, HH, true ><<<dim3(2560), dim3(256), 0, stream>>>((const void*)mid, (void*)out);
  } else {
    vpass<<<dim3(2 * (HH / RV) * 64), dim3(256), 0, stream>>>(x, out);
    hpass<<<dim3(64 * HH / 2), dim3(256), 0, stream>>>(out);
  }
}

// Round 4
// 293.935 us; speedup vs baseline: 1.6379x; 1.1989x over previous
//
#include <hip/hip_runtime.h>

// ============================================================================
// GaussianBlur2D: separable 201-tap Gaussian (sigma=25, zero-pad), fp32 I/O.
// T=64, H=544, W=960.
//
// v4: barrier-free direct-fragment streaming on v_mfma_f32_16x16x32_f16.
//   - B-fragments loaded STRAIGHT from global: lane l loads rows 8*(l>>4)+j,
//     col (l&15) -> per instr 4 rows x 16 cols x 4B = 4 full sectors. No LDS
//     transpose, no barriers, no staging redundancy (each element read once).
//   - A-fragments (Toeplitz taps): the same 15 half8 values every K-step
//     (u = i-2t in [-13,1]) -> held in 60 VGPRs, loaded once from LDS table.
//   - K-loop fully unrolled (t compile-time): acc[2t+u], prefetch set [t&1],
//     all indices static (no scratch). 2-deep named prefetch; compiler emits
//     counted vmcnt (nothing in the loop forces a drain).
//   - M per block: pass1 = full 544 (34 acc), pass2 = 480 x2 kernels (30 acc).
//   - edge K-steps (<=2 per kernel) use clamped addresses + zero masks.
// pass1: fp32 -> f16 intermediate (transposed [t][w][h] in d_ws)
// pass2: f16 -> fp32 final (transposed back). Numerics identical to v2/v3.
// Fallback: if ws_size < 67MB, previous verified fp32 vpass/hpass (472us).
// ============================================================================

typedef _Float16 half8 __attribute__((ext_vector_type(8)));
typedef float    f32x4 __attribute__((ext_vector_type(4)));
typedef unsigned short u16;
typedef unsigned int   u32;
typedef u32 u32x4 __attribute__((ext_vector_type(4)));

#define HH   544
#define WWD  960
#define PADC 100
#define RV   32

// ---- compile-time Gaussian (double Taylor exp, rounded to f32) ----
constexpr double cexp_taylor(double x) {
  double term = 1.0, sum = 1.0;
  for (int n = 1; n < 120; ++n) { term *= x / n; sum += term; }
  return sum;
}
constexpr float gaussk(int k) {            // tap k in [0,200] -> g(k-100), else 0
  if (k < 0 || k > 200) return 0.0f;
  double r = (double)(k - PADC);
  return (float)(cexp_taylor(-(r * r) / (2.0 * 25.0 * 25.0))
                 / (25.0 * 2.5066282746310002));
}

// zero-padded tap table: G0.v[v] = gaussk(v - 40), v in [0,288)
struct G0T { float v[288]; };
constexpr G0T make_g0() {
  G0T t{};
  for (int i = 0; i < 288; ++i) t.v[i] = gaussk(i - 40);
  return t;
}
__device__ __constant__ G0T G0 = make_g0();

__device__ __forceinline__ u16 f16u(float x) {
  return __builtin_bit_cast(u16, (_Float16)x);   // RNE
}

// ============================================================================
// Transposing banded conv, barrier-free streaming (layouts verified r1-r3):
//   in : 64 frames [R][C] row-major, conv along R (201 taps, zero-pad)
//   out: 64 frames [C][R]   out[t][c][r] = sum_b g(b) in[t][r+b-100][c]
// Block: 256 thr = 4 independent waves; wave owns 16 cols x rows [M0,M0+16NI).
// K-step t stages rows kb..kb+31, kb = M0-100+32t; active u=i-2t in [-13,1].
// A-frag: af[u+13] (registers). B-frag: direct global loads (see header).
// C/D: col=lane&15, row=4*(lane>>4)+reg.
// ============================================================================
template<int R, int C, int NCG, int M0, int NI, int T_LO, int T_HI, bool IN16>
__global__ __launch_bounds__(256, 2) void gconv4(const void* __restrict__ inv,
                                                 void* __restrict__ outv) {
  const int tid = threadIdx.x;
  const int l   = tid & 63, wv = tid >> 6;
  const int n16 = l & 15,  g4 = l >> 4;

  // ---- build tap-fragment table in LDS, then hoist to registers ----
  __shared__ uint4 PF[15][64];
  for (int E = tid; E < 960; E += 256) {
    const int le = E & 63, uq = E >> 6;
    const int bas = (le & 15) - 8 * (le >> 4) + 16 * uq + 32;
    u32 w[4];
#pragma unroll
    for (int p = 0; p < 4; ++p) {
      const u16 h0 = f16u(G0.v[bas - 2 * p] * 1024.0f);
      const u16 h1 = f16u(G0.v[bas - 2 * p - 1] * 1024.0f);
      w[p] = (u32)h0 | ((u32)h1 << 16);
    }
    uint4 q; q.x = w[0]; q.y = w[1]; q.z = w[2]; q.w = w[3];
    PF[uq][le] = q;
  }
  __syncthreads();                          // only barrier in the kernel

  half8 af[15];
#pragma unroll
  for (int u = 0; u < 15; ++u)
    af[u] = *reinterpret_cast<const half8*>(&PF[u][l]);

  const int bI = blockIdx.x;
  const int tf = bI / NCG;
  const int cg = bI - tf * NCG;
  const int colbase = cg * 64 + wv * 16;
  int cc = colbase + n16;                   // clamp for pass2 col tail
  if (cc > C - 1) cc = C - 1;

  const size_t fofs = (size_t)tf * R * C;
  const float* __restrict__ pF = (const float*)inv + fofs;
  const u16*   __restrict__ pH = (const u16*)inv + fofs;

  int vof[8];                               // per-lane frag offsets (constant)
#pragma unroll
  for (int j = 0; j < 8; ++j) vof[j] = (8 * g4 + j) * C + cc;

  f32x4 acc[NI];
#pragma unroll
  for (int i = 0; i < NI; ++i) acc[i] = (f32x4){0.f, 0.f, 0.f, 0.f};

  float lf[2][8];                           // named prefetch sets (pass1)
  u16   lh[2][8];                           // named prefetch sets (pass2)

  auto LOAD = [&](int t, int s) {           // called with unroll-constant args
    const int kb = M0 - PADC + 32 * t;
    const bool edge = (kb < 0) || (kb + 31 > R - 1);
    if (!edge) {
      if constexpr (!IN16) {
        const float* pT = pF + (ptrdiff_t)kb * C;
#pragma unroll
        for (int j = 0; j < 8; ++j) lf[s][j] = pT[vof[j]];
      } else {
        const u16* pT = pH + (ptrdiff_t)kb * C;
#pragma unroll
        for (int j = 0; j < 8; ++j) lh[s][j] = pT[vof[j]];
      }
    } else {                                // <=2 steps per kernel: clamp+mask
#pragma unroll
      for (int j = 0; j < 8; ++j) {
        const int rr  = kb + 8 * g4 + j;
        const int rcl = rr < 0 ? 0 : (rr > R - 1 ? R - 1 : rr);
        const bool ok = (rr == rcl);
        if constexpr (!IN16) {
          const float v = pF[(size_t)rcl * C + cc];
          lf[s][j] = ok ? v : 0.0f;
        } else {
          const u16 v = pH[(size_t)rcl * C + cc];
          lh[s][j] = ok ? v : (u16)0;
        }
      }
    }
  };

  auto STEP = [&](int t) {
    const int s = t & 1;
    half8 bf;
    if constexpr (!IN16) {                  // fp32 -> f16 fragment
#pragma unroll
      for (int j = 0; j < 8; ++j) bf[j] = (_Float16)lf[s][j];
    } else {                                // bit-pack f16 fragment
      u32x4 wq;
      wq[0] = (u32)lh[s][0] | ((u32)lh[s][1] << 16);
      wq[1] = (u32)lh[s][2] | ((u32)lh[s][3] << 16);
      wq[2] = (u32)lh[s][4] | ((u32)lh[s][5] << 16);
      wq[3] = (u32)lh[s][6] | ((u32)lh[s][7] << 16);
      bf = __builtin_bit_cast(half8, wq);
    }
    if (t + 2 <= T_HI) LOAD(t + 2, s);      // refill this set, 2 steps ahead
#pragma unroll
    for (int u = -13; u <= 1; ++u) {
      const int i = 2 * t + u;              // compile-time (t unrolled)
      if (i >= 0 && i < NI)
        acc[i] = __builtin_amdgcn_mfma_f32_16x16x32_f16(af[u + 13], bf, acc[i], 0, 0, 0);
    }
  };

  LOAD(T_LO, T_LO & 1);
  if (T_LO + 1 <= T_HI) LOAD(T_LO + 1, (T_LO + 1) & 1);
#pragma unroll
  for (int t = T_LO; t <= T_HI; ++t) STEP(t);

  // ---- transposed store: out[t][c][r]; lane holds 4 consecutive r ----
  const float SDE = 1.0f / 1024.0f;         // undo tap scale (exact pow2)
  const int c_out = colbase + n16;
  if (((C % 64) == 0) || (c_out < C)) {
    if constexpr (!IN16) {                  // pass 1: f16 intermediate
      u16* of = (u16*)outv + fofs + (size_t)c_out * R;
#pragma unroll
      for (int i = 0; i < NI; ++i) {
        const int r0 = M0 + 16 * i + 4 * g4;
        uint2 o;
        o.x = (u32)f16u(acc[i][0] * SDE) | ((u32)f16u(acc[i][1] * SDE) << 16);
        o.y = (u32)f16u(acc[i][2] * SDE) | ((u32)f16u(acc[i][3] * SDE) << 16);
        *(uint2*)(of + r0) = o;
      }
    } else {                                // pass 2: fp32 final output
      float* of = (float*)outv + fofs + (size_t)c_out * R;
#pragma unroll
      for (int i = 0; i < NI; ++i) {
        const int r0 = M0 + 16 * i + 4 * g4;
        float4 o;
        o.x = acc[i][0] * SDE; o.y = acc[i][1] * SDE;
        o.z = acc[i][2] * SDE; o.w = acc[i][3] * SDE;
        *(float4*)(of + r0) = o;
      }
    }
  }
}

// ============================================================================
// Fallback fp32 path (verified, 472us) — only if workspace too small.
// ============================================================================
struct KTabZ { float v[272]; };
constexpr KTabZ make_ktz() {
  KTabZ t{};
  for (int i = 0; i < 272; ++i) t.v[i] = gaussk(i - 31);
  return t;
}
__device__ __constant__ KTabZ KTZ = make_ktz();

struct KTabE { float v[216]; };
constexpr KTabE make_kte() {
  KTabE t{};
  for (int i = 0; i < 216; ++i) t.v[i] = gaussk(i - 8);
  return t;
}
__device__ __constant__ KTabE KTE = make_kte();

__global__ __launch_bounds__(256, 4) void vpass(const float* __restrict__ x,
                                                float* __restrict__ y) {
  const int lid = blockIdx.x;
  const int xcd = lid & 7;
  const int s   = lid >> 3;
  const int f   = s / 34;
  const int r34 = s - 34 * f;
  const int t   = (f << 3) | xcd;
  const int wt  = r34 & 1;
  const int hc  = r34 >> 1;
  const int tid = threadIdx.x;
  const int w   = 2 * (wt * 256 + tid);
  const int h0  = hc * RV;
  if (w >= WWD) return;

  const float* xw = x + (size_t)t * (HH * WWD) + w;

  float ax[RV], ay[RV];
#pragma unroll
  for (int r = 0; r < RV; ++r) { ax[r] = 0.f; ay[r] = 0.f; }

#pragma unroll 8
  for (int bb = 0; bb < 232; ++bb) {
    const int h  = h0 + bb - PADC;
    const int hcl = (h < 0) ? 0 : ((h > HH - 1) ? HH - 1 : h);
    const float m = (h == hcl) ? 1.0f : 0.0f;
    float2 v = *(const float2*)(xw + (size_t)hcl * WWD);
    v.x *= m; v.y *= m;
    const float* kb = &KTZ.v[bb + 31];
#pragma unroll
    for (int r = 0; r < RV; ++r) {
      const float kk = kb[-r];
      ax[r] = fmaf(kk, v.x, ax[r]);
      ay[r] = fmaf(kk, v.y, ay[r]);
    }
  }

  float* yp = y + (size_t)t * (HH * WWD) + (size_t)h0 * WWD + w;
#pragma unroll
  for (int r = 0; r < RV; ++r) {
    float2 o; o.x = ax[r]; o.y = ay[r];
    *(float2*)(yp + (size_t)r * WWD) = o;
  }
}

__device__ __forceinline__ int swz(int q) { return q ^ ((q >> 3) & 1); }

__global__ __launch_bounds__(256, 4) void hpass(float* __restrict__ y) {
  __shared__ __align__(16) float4 row[2][292];
  const int tid = threadIdx.x;
  const int hh  = tid >> 7;
  const int lt  = tid & 127;
  float* yp = y + (size_t)(blockIdx.x * 2 + hh) * WWD;

  const float4 z4 = {0.f, 0.f, 0.f, 0.f};
  if (lt < 25) {
    row[hh][swz(lt)] = z4;
  } else if (lt >= 32 && lt < 57) {
    row[hh][swz(265 + lt - 32)] = z4;
  }
  if (lt < 120) {
    const int q0 = 25 + 2 * lt;
    row[hh][swz(q0)]     = *(const float4*)(yp + 8 * lt);
    row[hh][swz(q0 + 1)] = *(const float4*)(yp + 8 * lt + 4);
  }
  __syncthreads();

  if (lt < 120) {
    float a0=0.f,a1=0.f,a2=0.f,a3=0.f,a4=0.f,a5=0.f,a6=0.f,a7=0.f;
#pragma unroll 4
    for (int j = 0; j < 52; ++j) {
      const float4 v = row[hh][swz(2 * lt + j)];
      const float* kb = &KTE.v[4 * j + 8];
      {
        const float xv = v.x;
        a0 = fmaf(kb[0], xv, a0);  a1 = fmaf(kb[-1], xv, a1);
        a2 = fmaf(kb[-2], xv, a2); a3 = fmaf(kb[-3], xv, a3);
        a4 = fmaf(kb[-4], xv, a4); a5 = fmaf(kb[-5], xv, a5);
        a6 = fmaf(kb[-6], xv, a6); a7 = fmaf(kb[-7], xv, a7);
      }
      {
        const float xv = v.y;
        a0 = fmaf(kb[1], xv, a0);  a1 = fmaf(kb[0], xv, a1);
        a2 = fmaf(kb[-1], xv, a2); a3 = fmaf(kb[-2], xv, a3);
        a4 = fmaf(kb[-3], xv, a4); a5 = fmaf(kb[-4], xv, a5);
        a6 = fmaf(kb[-5], xv, a6); a7 = fmaf(kb[-6], xv, a7);
      }
      {
        const float xv = v.z;
        a0 = fmaf(kb[2], xv, a0);  a1 = fmaf(kb[1], xv, a1);
        a2 = fmaf(kb[0], xv, a2);  a3 = fmaf(kb[-1], xv, a3);
        a4 = fmaf(kb[-2], xv, a4); a5 = fmaf(kb[-3], xv, a5);
        a6 = fmaf(kb[-4], xv, a6); a7 = fmaf(kb[-5], xv, a7);
      }
      {
        const float xv = v.w;
        a0 = fmaf(kb[3], xv, a0);  a1 = fmaf(kb[2], xv, a1);
        a2 = fmaf(kb[1], xv, a2);  a3 = fmaf(kb[0], xv, a3);
        a4 = fmaf(kb[-1], xv, a4); a5 = fmaf(kb[-2], xv, a5);
        a6 = fmaf(kb[-3], xv, a6); a7 = fmaf(kb[-4], xv, a7);
      }
    }
    float4 o0; o0.x = a0; o0.y = a1; o0.z = a2; o0.w = a3;
    float4 o1; o1.x = a4; o1.y = a5; o1.z = a6; o1.w = a7;
    *(float4*)(yp + 8 * lt)     = o0;
    *(float4*)(yp + 8 * lt + 4) = o1;
  }
}

extern "C" void kernel_launch(void* const* d_in, const int* in_sizes, int n_in,
                              void* d_out, int out_size, void* d_ws, size_t ws_size,
                              hipStream_t stream) {
  const float* x = (const float*)d_in[0];
  float* out = (float*)d_out;
  (void)in_sizes; (void)n_in; (void)out_size;

  const size_t ws_need = (size_t)64 * HH * WWD * sizeof(u16);  // 66.8 MB
  if (d_ws != nullptr && ws_size >= ws_need) {
    u16* mid = (u16*)d_ws;
    // pass 1: conv over H (R=544), fp32 -> f16 transposed [t][w][h]
    //         64 frames x 15 col-groups, full column span (NI=34, t=3..20)
    gconv4<HH, WWD, 15, 0, 34, 3, 20, false>
        <<<dim3(960), dim3(256), 0, stream>>>((const void*)x, (void*)mid);
    // pass 2: conv over W (R=960) on transposed mid, f16 -> fp32 final.
    //         Two M-halves (NI=30 each), 64 frames x 9 col-groups.
    gconv4<WWD, HH, 9, 0,   30, 3, 21, true>
        <<<dim3(576), dim3(256), 0, stream>>>((const void*)mid, (void*)out);
    gconv4<WWD, HH, 9, 480, 30, 0, 18, true>
        <<<dim3(576), dim3(256), 0, stream>>>((const void*)mid, (void*)out);
  } else {
    vpass<<<dim3(2 * (HH / RV) * 64), dim3(256), 0, stream>>>(x, out);
    hpass<<<dim3(64 * HH / 2), dim3(256), 0, stream>>>(out);
  }
}